// Round 1
// baseline (401.201 us; speedup 1.0000x reference)
//
#include <hip/hip_runtime.h>
#include <stdint.h>

// Problem constants (fixed shapes)
#define BB 4
#define TT 4096
#define DD 1024
#define HH 1024
#define MM (BB * TT)      // 16384
#define NC 64             // scan chunks
#define CL (TT / NC)      // 64 steps per chunk

typedef __bf16 bf16x8 __attribute__((ext_vector_type(8)));
typedef float f32x4 __attribute__((ext_vector_type(4)));

// ---------------- helpers ----------------

__device__ __forceinline__ unsigned short f2bf(float f) {
    unsigned u = __float_as_uint(f);
    u += 0x7fffu + ((u >> 16) & 1u);   // round-to-nearest-even
    return (unsigned short)(u >> 16);
}

__device__ __forceinline__ float softplusf(float x) {
    return (x > 15.f) ? x : log1pf(__expf(x));
}

__device__ __forceinline__ float g_fn(float x) {
    return (x >= 0.f) ? (x + 0.5f) : 1.0f / (1.0f + __expf(-x));
}

// async global->LDS, 16B per lane. LDS dest = wave-uniform base + lane*16.
// Integer round-trip avoids pointer addrspace-cast issues; as(3) ptr is 32-bit
// so the flat LDS address truncates to the LDS offset (standard CK idiom).
__device__ __forceinline__ void async_copy16(const void* gsrc, void* ldst) {
    __builtin_amdgcn_global_load_lds(
        reinterpret_cast<__attribute__((address_space(1))) unsigned int*>(
            reinterpret_cast<uintptr_t>(gsrc)),
        reinterpret_cast<__attribute__((address_space(3))) unsigned int*>(
            reinterpret_cast<uintptr_t>(ldst)),
        16, 0, 0);
}

// ---------------- cast kernels ----------------

__global__ void cast_x_kernel(const float* __restrict__ src,
                              unsigned short* __restrict__ dst, int n4) {
    int i = blockIdx.x * 256 + threadIdx.x;
    if (i >= n4) return;
    float4 v = reinterpret_cast<const float4*>(src)[i];
    ushort4 o;
    o.x = f2bf(v.x); o.y = f2bf(v.y); o.z = f2bf(v.z); o.w = f2bf(v.w);
    reinterpret_cast<ushort4*>(dst)[i] = o;
}

__global__ void cast_w_kernel(const float* __restrict__ Wf,
                              const float* __restrict__ Wi,
                              const float* __restrict__ Wh,
                              unsigned short* __restrict__ dst) {
    int gi = blockIdx.x * 256 + threadIdx.x;        // 0 .. 786431 (3 * 2^18)
    int which = gi >> 18;
    int j = gi & 262143;
    const float* s = (which == 0) ? Wf : ((which == 1) ? Wi : Wh);
    float4 v = reinterpret_cast<const float4*>(s)[j];
    ushort4 o;
    o.x = f2bf(v.x); o.y = f2bf(v.y); o.z = f2bf(v.z); o.w = f2bf(v.w);
    reinterpret_cast<ushort4*>(dst)[(which << 18) + j] = o;
}

// ---------------- fused 3-gate GEMM + gate math ----------------
// Block tile: 128 (m) x 64 (h), all 3 gates. 4 waves in 2x2; each wave does
// 64(m) x 32(h) per gate = 4x2 tiles of 16x16, 3 gates -> 96 acc VGPRs/lane.
// A = xb [16384,1024] bf16 (K-contig), B = Wb [3*1024,1024] bf16 (K-contig).
// Epilogue computes f = sigmoid(-(sp(-zf)-sp(-zi))), v = (1-f)*g(zh).

__global__ __launch_bounds__(256, 2) void gemm_gates(
    const unsigned short* __restrict__ xb,
    const unsigned short* __restrict__ Wb,
    const float* __restrict__ bf_p, const float* __restrict__ bi_p,
    const float* __restrict__ bh_p,
    float* __restrict__ F, float* __restrict__ V) {
    __shared__ short As[128 * 64];      // 16 KB
    __shared__ short Bs[3 * 64 * 64];   // 24 KB

    const int tid  = threadIdx.x;
    const int wave = tid >> 6;
    const int lane = tid & 63;
    const int bh   = blockIdx.x;        // h-tile  [0,16)
    const int bm   = blockIdx.y;        // m-tile  [0,128)
    const int wm   = wave >> 1;         // 0..1
    const int wh   = wave & 1;          // 0..1

    const int lr8 = lane >> 3;          // 0..7  (row within 8-row segment)
    const int lc  = (lane & 7) * 8;     // element col within 64-wide K slab

    f32x4 acc[3][4][2];
#pragma unroll
    for (int g = 0; g < 3; ++g)
#pragma unroll
        for (int mt = 0; mt < 4; ++mt)
#pragma unroll
            for (int nt = 0; nt < 2; ++nt)
                acc[g][mt][nt] = (f32x4){0.f, 0.f, 0.f, 0.f};

    for (int k0 = 0; k0 < DD; k0 += 64) {
        // ---- stage A (16 segs) + B (24 segs), 1KB per wave-call ----
        for (int s = wave; s < 40; s += 4) {
            if (s < 16) {
                int row = s * 8 + lr8;
                const unsigned short* g =
                    xb + (size_t)(bm * 128 + row) * DD + k0 + lc;
                async_copy16(g, (void*)(As + s * 512));
            } else {
                int u = s - 16;
                int gate = u >> 3, r8 = u & 7;
                int row = r8 * 8 + lr8;
                const unsigned short* g =
                    Wb + (size_t)(gate * HH + bh * 64 + row) * DD + k0 + lc;
                async_copy16(g, (void*)(Bs + u * 512));
            }
        }
        __syncthreads();   // drains vmcnt -> LDS valid

        // ---- compute: 2 k-steps of 16x16x32 ----
#pragma unroll
        for (int ks = 0; ks < 2; ++ks) {
            const int kk = ks * 32 + (lane >> 4) * 8;
            const int ar = wm * 64 + (lane & 15);
            const int br = wh * 32 + (lane & 15);
            bf16x8 af[4];
#pragma unroll
            for (int mt = 0; mt < 4; ++mt)
                af[mt] = *reinterpret_cast<const bf16x8*>(
                    As + (ar + mt * 16) * 64 + kk);
            bf16x8 bfr[3][2];
#pragma unroll
            for (int g = 0; g < 3; ++g)
#pragma unroll
                for (int nt = 0; nt < 2; ++nt)
                    bfr[g][nt] = *reinterpret_cast<const bf16x8*>(
                        Bs + g * 4096 + (br + nt * 16) * 64 + kk);
#pragma unroll
            for (int g = 0; g < 3; ++g)
#pragma unroll
                for (int mt = 0; mt < 4; ++mt)
#pragma unroll
                    for (int nt = 0; nt < 2; ++nt)
                        acc[g][mt][nt] = __builtin_amdgcn_mfma_f32_16x16x32_bf16(
                            af[mt], bfr[g][nt], acc[g][mt][nt], 0, 0, 0);
        }
        __syncthreads();   // all waves done reading before restage
    }

    // ---- epilogue: bias + normalized gates, write f and v ----
    const int m0  = bm * 128 + wm * 64 + (lane >> 4) * 4;
    const int h0i = bh * 64 + wh * 32 + (lane & 15);
#pragma unroll
    for (int nt = 0; nt < 2; ++nt) {
        const int h = h0i + nt * 16;
        const float bfs = bf_p[h], bis = bi_p[h], bhs = bh_p[h];
#pragma unroll
        for (int mt = 0; mt < 4; ++mt) {
#pragma unroll
            for (int r = 0; r < 4; ++r) {
                const int m = m0 + mt * 16 + r;
                float zf = acc[0][mt][nt][r] + bfs;
                float zi = acc[1][mt][nt][r] + bis;
                float zh = acc[2][mt][nt][r] + bhs;
                float d  = softplusf(-zf) - softplusf(-zi);
                float f  = 1.0f / (1.0f + __expf(d));   // sigmoid(-d)
                float iv = 1.0f - f;                    // sigmoid(d)
                float gg = g_fn(zh);
                size_t o = (size_t)m * HH + h;
                F[o] = f;
                V[o] = iv * gg;
            }
        }
    }
}

// ---------------- scan (3-pass chunked linear scan) ----------------
// h_t = f_t * h_{t-1} + v_t ; convex combination -> stable in fp32.

__global__ void scan1_kernel(const float* __restrict__ F,
                             const float* __restrict__ V,
                             float* __restrict__ Fc, float* __restrict__ Vc) {
    const int bx = blockIdx.x, tid = threadIdx.x;
    const int hb = bx & 3, c = (bx >> 2) & (NC - 1), b = bx >> 8;
    const int h = hb * 256 + tid;
    size_t base = ((size_t)(b * TT + c * CL)) * HH + h;
    float Fp = 1.f, hv = 0.f;
#pragma unroll 8
    for (int s = 0; s < CL; ++s) {
        float f = F[base + (size_t)s * HH];
        float v = V[base + (size_t)s * HH];
        hv = fmaf(f, hv, v);
        Fp *= f;
    }
    int ci = (b * NC + c) * HH + h;
    Fc[ci] = Fp;
    Vc[ci] = hv;
}

__global__ void scan2_kernel(const float* __restrict__ h0,
                             const float* __restrict__ Fc,
                             const float* __restrict__ Vc,
                             float* __restrict__ Hin) {
    const int gid = blockIdx.x * 256 + threadIdx.x;   // 0..4095
    const int b = gid >> 10, h = gid & (HH - 1);
    float carry = g_fn(h0[gid]);
#pragma unroll 8
    for (int c = 0; c < NC; ++c) {
        int ci = (b * NC + c) * HH + h;
        Hin[ci] = carry;
        carry = fmaf(Fc[ci], carry, Vc[ci]);
    }
    (void)b;
}

__global__ void scan3_kernel(const float* __restrict__ F,
                             const float* __restrict__ Hin,
                             float* __restrict__ V) {
    const int bx = blockIdx.x, tid = threadIdx.x;
    const int hb = bx & 3, c = (bx >> 2) & (NC - 1), b = bx >> 8;
    const int h = hb * 256 + tid;
    size_t base = ((size_t)(b * TT + c * CL)) * HH + h;
    float carry = Hin[(b * NC + c) * HH + h];
#pragma unroll 8
    for (int s = 0; s < CL; ++s) {
        size_t idx = base + (size_t)s * HH;
        carry = fmaf(F[idx], carry, V[idx]);
        V[idx] = carry;   // in-place: v -> h
    }
}

// ---------------- launch ----------------

extern "C" void kernel_launch(void* const* d_in, const int* in_sizes, int n_in,
                              void* d_out, int out_size, void* d_ws, size_t ws_size,
                              hipStream_t stream) {
    const float* x   = (const float*)d_in[0];
    const float* h0  = (const float*)d_in[1];
    const float* Wf  = (const float*)d_in[2];
    const float* bfp = (const float*)d_in[3];
    const float* Wi  = (const float*)d_in[4];
    const float* bip = (const float*)d_in[5];
    const float* Wh  = (const float*)d_in[6];
    const float* bhp = (const float*)d_in[7];
    float* out = (float*)d_out;

    char* ws = (char*)d_ws;
    unsigned short* xb = (unsigned short*)ws;                   // 32 MiB bf16 x
    unsigned short* Wb = (unsigned short*)(ws + 33554432);      // 6 MiB bf16 W concat
    float* F   = (float*)(ws + 39845888);                       // 64 MiB gate f
    float* Fc  = (float*)(ws + 106954752);                      // 1 MiB
    float* Vc  = (float*)(ws + 108003328);                      // 1 MiB
    float* Hin = (float*)(ws + 109051904);                      // 1 MiB

    cast_x_kernel<<<16384, 256, 0, stream>>>(x, xb, MM * DD / 4);
    cast_w_kernel<<<3072, 256, 0, stream>>>(Wf, Wi, Wh, Wb);
    gemm_gates<<<dim3(HH / 64, MM / 128), 256, 0, stream>>>(xb, Wb, bfp, bip, bhp,
                                                            F, out);
    scan1_kernel<<<BB * NC * (HH / 256), 256, 0, stream>>>(F, out, Fc, Vc);
    scan2_kernel<<<16, 256, 0, stream>>>(h0, Fc, Vc, Hin);
    scan3_kernel<<<BB * NC * (HH / 256), 256, 0, stream>>>(F, Hin, out);
}

// Round 2
// 395.658 us; speedup vs baseline: 1.0140x; 1.0140x over previous
//
#include <hip/hip_runtime.h>
#include <stdint.h>

// Problem constants (fixed shapes)
#define BB 4
#define TT 4096
#define DD 1024
#define HH 1024
#define MM (BB * TT)      // 16384
#define NC 128            // scan chunks
#define CL (TT / NC)      // 32 steps per chunk

typedef __bf16 bf16x8 __attribute__((ext_vector_type(8)));
typedef float f32x4 __attribute__((ext_vector_type(4)));

// ---------------- helpers ----------------

__device__ __forceinline__ unsigned short f2bf(float f) {
    unsigned u = __float_as_uint(f);
    u += 0x7fffu + ((u >> 16) & 1u);   // round-to-nearest-even
    return (unsigned short)(u >> 16);
}

__device__ __forceinline__ float softplusf(float x) {
    return (x > 15.f) ? x : log1pf(__expf(x));
}

__device__ __forceinline__ float g_fn(float x) {
    return (x >= 0.f) ? (x + 0.5f) : 1.0f / (1.0f + __expf(-x));
}

// async global->LDS, 16B per lane; hardware dest = wave-uniform base + lane*16
__device__ __forceinline__ void async_copy16(const void* gsrc, void* ldst) {
    __builtin_amdgcn_global_load_lds(
        reinterpret_cast<__attribute__((address_space(1))) unsigned int*>(
            reinterpret_cast<uintptr_t>(gsrc)),
        reinterpret_cast<__attribute__((address_space(3))) unsigned int*>(
            reinterpret_cast<uintptr_t>(ldst)),
        16, 0, 0);
}

// ---------------- cast kernels ----------------

__global__ void cast_x_kernel(const float* __restrict__ src,
                              unsigned short* __restrict__ dst, int n4) {
    int i = blockIdx.x * 256 + threadIdx.x;
    if (i >= n4) return;
    float4 v = reinterpret_cast<const float4*>(src)[i];
    ushort4 o;
    o.x = f2bf(v.x); o.y = f2bf(v.y); o.z = f2bf(v.z); o.w = f2bf(v.w);
    reinterpret_cast<ushort4*>(dst)[i] = o;
}

__global__ void cast_w_kernel(const float* __restrict__ Wf,
                              const float* __restrict__ Wi,
                              const float* __restrict__ Wh,
                              unsigned short* __restrict__ dst) {
    int gi = blockIdx.x * 256 + threadIdx.x;        // 0 .. 786431 (3 * 2^18)
    int which = gi >> 18;
    int j = gi & 262143;
    const float* s = (which == 0) ? Wf : ((which == 1) ? Wi : Wh);
    float4 v = reinterpret_cast<const float4*>(s)[j];
    ushort4 o;
    o.x = f2bf(v.x); o.y = f2bf(v.y); o.z = f2bf(v.z); o.w = f2bf(v.w);
    reinterpret_cast<ushort4*>(dst)[(which << 18) + j] = o;
}

// ---------------- fused 3-gate GEMM + gate math ----------------
// Block tile: 128 (m) x 64 (h), all 3 gates. 4 waves in 2x2; each wave does
// 64(m) x 32(h) per gate = 4x2 tiles of 16x16, 3 gates -> 96 acc regs/lane.
// LDS layout is XOR-swizzled: within each 64-elem (128 B) row, 16 B chunk c
// holds global chunk c ^ (row & 7).  Staging applies the swizzle on the
// GLOBAL source column (global_load_lds writes base + lane*16, fixed);
// read side: lane-constant chunk, and ks=1 is addr ^ 64.

__global__ __launch_bounds__(256, 2) void gemm_gates(
    const unsigned short* __restrict__ xb,
    const unsigned short* __restrict__ Wb,
    const float* __restrict__ bf_p, const float* __restrict__ bi_p,
    const float* __restrict__ bh_p,
    float* __restrict__ F, float* __restrict__ V) {
    __shared__ short As[16 * 512];      // 16 KB : 128 rows x 64
    __shared__ short Bs[24 * 512];      // 24 KB : 3 gates x 64 rows x 64

    const int tid  = threadIdx.x;
    const int wave = tid >> 6;
    const int lane = tid & 63;
    const int bh   = blockIdx.x;        // h-tile  [0,16)
    const int bm   = blockIdx.y;        // m-tile  [0,128)
    const int wm   = wave >> 1;         // 0..1
    const int wh   = wave & 1;          // 0..1

    // ---- staging constants: lane writes LDS row lr, chunk (lane&7);
    //      must fetch global chunk (lane&7) ^ lr  (swizzle) ----
    const int lr = lane >> 3;                     // 0..7
    const int gc = (((lane & 7) ^ lr) << 3);      // global col, elements

    // 10 segments per wave: 4 of A, 6 of B (fixed assignment)
    const unsigned short* gptr[10];
    short* lptr[10];
#pragma unroll
    for (int j = 0; j < 10; ++j) {
        int s = wave + j * 4;
        if (s < 16) {
            int row = bm * 128 + s * 8 + lr;
            gptr[j] = xb + (size_t)row * DD + gc;
            lptr[j] = As + s * 512;
        } else {
            int u = s - 16;                       // 0..23
            int row = (u >> 3) * HH + bh * 64 + (u & 7) * 8 + lr;
            gptr[j] = Wb + (size_t)row * DD + gc;
            lptr[j] = Bs + u * 512;
        }
    }

    // ---- compute-side lane constants (byte offsets into LDS) ----
    const int pc   = (((lane >> 4) ^ (lane & 7)) << 4);   // ks=0 chunk offset
    const int arow = (wm * 64 + (lane & 15)) * 128;       // A row byte offset
    const int brow = (wh * 32 + (lane & 15)) * 128;       // B row byte offset
    const char* Ab = (const char*)As;
    const char* Bb = (const char*)Bs;

    f32x4 acc[3][4][2];
#pragma unroll
    for (int g = 0; g < 3; ++g)
#pragma unroll
        for (int mt = 0; mt < 4; ++mt)
#pragma unroll
            for (int nt = 0; nt < 2; ++nt)
                acc[g][mt][nt] = (f32x4){0.f, 0.f, 0.f, 0.f};

    for (int kb = 0; kb < 16; ++kb) {
#pragma unroll
        for (int j = 0; j < 10; ++j) async_copy16(gptr[j], lptr[j]);
        __syncthreads();   // drains vmcnt -> LDS valid

#pragma unroll
        for (int ks = 0; ks < 2; ++ks) {
            const int px = pc ^ (ks << 6);        // ks=1: flip chunk bit 2
            bf16x8 af[4];
#pragma unroll
            for (int mt = 0; mt < 4; ++mt)
                af[mt] = *reinterpret_cast<const bf16x8*>(Ab + arow + mt * 2048 + px);
            bf16x8 bfr[3][2];
#pragma unroll
            for (int g = 0; g < 3; ++g)
#pragma unroll
                for (int nt = 0; nt < 2; ++nt)
                    bfr[g][nt] = *reinterpret_cast<const bf16x8*>(
                        Bb + g * 8192 + brow + nt * 2048 + px);
#pragma unroll
            for (int g = 0; g < 3; ++g)
#pragma unroll
                for (int mt = 0; mt < 4; ++mt)
#pragma unroll
                    for (int nt = 0; nt < 2; ++nt)
                        acc[g][mt][nt] = __builtin_amdgcn_mfma_f32_16x16x32_bf16(
                            af[mt], bfr[g][nt], acc[g][mt][nt], 0, 0, 0);
        }
        __syncthreads();   // all waves done reading before restage
#pragma unroll
        for (int j = 0; j < 10; ++j) gptr[j] += 64;   // next 64-elem K slab
    }

    // ---- epilogue: bias + normalized gates, write f and v ----
    const int m0  = bm * 128 + wm * 64 + (lane >> 4) * 4;
    const int h0i = bh * 64 + wh * 32 + (lane & 15);
#pragma unroll
    for (int nt = 0; nt < 2; ++nt) {
        const int h = h0i + nt * 16;
        const float bfs = bf_p[h], bis = bi_p[h], bhs = bh_p[h];
#pragma unroll
        for (int mt = 0; mt < 4; ++mt) {
#pragma unroll
            for (int r = 0; r < 4; ++r) {
                const int m = m0 + mt * 16 + r;
                float zf = acc[0][mt][nt][r] + bfs;
                float zi = acc[1][mt][nt][r] + bis;
                float zh = acc[2][mt][nt][r] + bhs;
                float d  = softplusf(-zf) - softplusf(-zi);
                float f  = 1.0f / (1.0f + __expf(d));   // sigmoid(-d)
                float iv = 1.0f - f;                    // sigmoid(d)
                float gg = g_fn(zh);
                size_t o = (size_t)m * HH + h;
                F[o] = f;
                V[o] = iv * gg;
            }
        }
    }
}

// ---------------- scan (3-pass chunked linear scan) ----------------
// h_t = f_t * h_{t-1} + v_t ; f+i=1 convex combination -> stable in fp32.
// float4 across h; NC=128 chunks of CL=32 steps.

__global__ void scan1_kernel(const float* __restrict__ F,
                             const float* __restrict__ V,
                             float* __restrict__ Fc, float* __restrict__ Vc) {
    const int bx = blockIdx.x, tid = threadIdx.x;
    const int c = bx & (NC - 1), b = bx >> 7;
    const float4* F4 = (const float4*)F;
    const float4* V4 = (const float4*)V;
    size_t base = ((size_t)(b * TT + c * CL) * HH) / 4 + tid;
    float4 Fp = {1.f, 1.f, 1.f, 1.f}, hv = {0.f, 0.f, 0.f, 0.f};
#pragma unroll 8
    for (int s = 0; s < CL; ++s) {
        float4 f = F4[base + (size_t)s * (HH / 4)];
        float4 v = V4[base + (size_t)s * (HH / 4)];
        hv.x = fmaf(f.x, hv.x, v.x); Fp.x *= f.x;
        hv.y = fmaf(f.y, hv.y, v.y); Fp.y *= f.y;
        hv.z = fmaf(f.z, hv.z, v.z); Fp.z *= f.z;
        hv.w = fmaf(f.w, hv.w, v.w); Fp.w *= f.w;
    }
    size_t ci = ((size_t)(b * NC + c) * HH) / 4 + tid;
    ((float4*)Fc)[ci] = Fp;
    ((float4*)Vc)[ci] = hv;
}

__global__ void scan2_kernel(const float* __restrict__ h0,
                             const float* __restrict__ Fc,
                             const float* __restrict__ Vc,
                             float* __restrict__ Hin) {
    const int gid = blockIdx.x * 256 + threadIdx.x;   // 0..4095
    const int b = gid >> 10, h = gid & (HH - 1);
    float carry = g_fn(h0[gid]);
#pragma unroll 8
    for (int c = 0; c < NC; ++c) {
        int ci = (b * NC + c) * HH + h;
        Hin[ci] = carry;
        carry = fmaf(Fc[ci], carry, Vc[ci]);
    }
}

__global__ void scan3_kernel(const float* __restrict__ F,
                             const float* __restrict__ Hin,
                             float* __restrict__ V) {
    const int bx = blockIdx.x, tid = threadIdx.x;
    const int c = bx & (NC - 1), b = bx >> 7;
    const float4* F4 = (const float4*)F;
    float4* V4 = (float4*)V;
    size_t base = ((size_t)(b * TT + c * CL) * HH) / 4 + tid;
    size_t ci = ((size_t)(b * NC + c) * HH) / 4 + tid;
    float4 carry = ((const float4*)Hin)[ci];
#pragma unroll 8
    for (int s = 0; s < CL; ++s) {
        size_t idx = base + (size_t)s * (HH / 4);
        float4 f = F4[idx];
        float4 v = V4[idx];
        carry.x = fmaf(f.x, carry.x, v.x);
        carry.y = fmaf(f.y, carry.y, v.y);
        carry.z = fmaf(f.z, carry.z, v.z);
        carry.w = fmaf(f.w, carry.w, v.w);
        V4[idx] = carry;   // in-place: v -> h
    }
}

// ---------------- launch ----------------

extern "C" void kernel_launch(void* const* d_in, const int* in_sizes, int n_in,
                              void* d_out, int out_size, void* d_ws, size_t ws_size,
                              hipStream_t stream) {
    const float* x   = (const float*)d_in[0];
    const float* h0  = (const float*)d_in[1];
    const float* Wf  = (const float*)d_in[2];
    const float* bfp = (const float*)d_in[3];
    const float* Wi  = (const float*)d_in[4];
    const float* bip = (const float*)d_in[5];
    const float* Wh  = (const float*)d_in[6];
    const float* bhp = (const float*)d_in[7];
    float* out = (float*)d_out;

    char* ws = (char*)d_ws;
    // xb [0,32M) and Wb [32M,38M) are dead after gemm; Fc/Vc/Hin alias xb.
    unsigned short* xb = (unsigned short*)ws;                   // 32 MiB bf16 x
    unsigned short* Wb = (unsigned short*)(ws + 33554432);      // 6 MiB bf16 W concat
    float* F   = (float*)(ws + 39845888);                       // 64 MiB gate f
    float* Fc  = (float*)(ws);                                  // 2 MiB (aliases xb)
    float* Vc  = (float*)(ws + 2097152);                        // 2 MiB
    float* Hin = (float*)(ws + 4194304);                        // 2 MiB

    cast_x_kernel<<<16384, 256, 0, stream>>>(x, xb, MM * DD / 4);
    cast_w_kernel<<<3072, 256, 0, stream>>>(Wf, Wi, Wh, Wb);
    gemm_gates<<<dim3(HH / 64, MM / 128), 256, 0, stream>>>(xb, Wb, bfp, bip, bhp,
                                                            F, out);
    scan1_kernel<<<BB * NC, 256, 0, stream>>>(F, out, Fc, Vc);
    scan2_kernel<<<16, 256, 0, stream>>>(h0, Fc, Vc, Hin);
    scan3_kernel<<<BB * NC, 256, 0, stream>>>(F, Hin, out);
}

// Round 3
// 375.899 us; speedup vs baseline: 1.0673x; 1.0526x over previous
//
#include <hip/hip_runtime.h>
#include <stdint.h>

// Problem constants (fixed shapes)
#define BB 4
#define TT 4096
#define DD 1024
#define HH 1024
#define MM (BB * TT)      // 16384
#define NC 128            // scan chunks
#define CL (TT / NC)      // 32 steps per chunk

typedef __bf16 bf16x8 __attribute__((ext_vector_type(8)));
typedef float f32x4 __attribute__((ext_vector_type(4)));

// ---------------- helpers ----------------

__device__ __forceinline__ unsigned short f2bf(float f) {
    unsigned u = __float_as_uint(f);
    u += 0x7fffu + ((u >> 16) & 1u);   // round-to-nearest-even
    return (unsigned short)(u >> 16);
}

__device__ __forceinline__ float bf2f(unsigned short u) {
    return __uint_as_float(((unsigned)u) << 16);
}

__device__ __forceinline__ float softplusf(float x) {
    return (x > 15.f) ? x : log1pf(__expf(x));
}

__device__ __forceinline__ float g_fn(float x) {
    return (x >= 0.f) ? (x + 0.5f) : 1.0f / (1.0f + __expf(-x));
}

// async global->LDS, 16B per lane; hardware dest = wave-uniform base + lane*16
__device__ __forceinline__ void async_copy16(const void* gsrc, void* ldst) {
    __builtin_amdgcn_global_load_lds(
        reinterpret_cast<__attribute__((address_space(1))) unsigned int*>(
            reinterpret_cast<uintptr_t>(gsrc)),
        reinterpret_cast<__attribute__((address_space(3))) unsigned int*>(
            reinterpret_cast<uintptr_t>(ldst)),
        16, 0, 0);
}

// ---------------- fused cast kernel ----------------

__global__ void cast_all(const float* __restrict__ x,
                         const float* __restrict__ Wf,
                         const float* __restrict__ Wi,
                         const float* __restrict__ Wh,
                         unsigned short* __restrict__ xb,
                         unsigned short* __restrict__ Wb) {
    const int NX = MM * DD / 4;                 // 4194304 float4s of x
    int i = blockIdx.x * 256 + threadIdx.x;
    if (i < NX) {
        float4 v = reinterpret_cast<const float4*>(x)[i];
        ushort4 o;
        o.x = f2bf(v.x); o.y = f2bf(v.y); o.z = f2bf(v.z); o.w = f2bf(v.w);
        reinterpret_cast<ushort4*>(xb)[i] = o;
    } else {
        int j = i - NX;                         // 0 .. 786431
        if (j < 3 * 262144) {
            int which = j >> 18, k = j & 262143;
            const float* s = (which == 0) ? Wf : ((which == 1) ? Wi : Wh);
            float4 v = reinterpret_cast<const float4*>(s)[k];
            ushort4 o;
            o.x = f2bf(v.x); o.y = f2bf(v.y); o.z = f2bf(v.z); o.w = f2bf(v.w);
            reinterpret_cast<ushort4*>(Wb)[(which << 18) + k] = o;
        }
    }
}

// ---------------- fused 3-gate GEMM + gate math ----------------
// Block tile: 128(m) x 64(h), 3 gates; 4 waves in 2x2, 96 acc regs/lane.
// XOR-swizzled LDS (conflict-free, verified R2). DOUBLE-BUFFERED staging:
// per K-iter: issue next tile's 10 global_load_lds, s_waitcnt vmcnt(10)
// (== my previous tile's loads complete), raw s_barrier (no compiler
// vmcnt(0) drain), compute, lgkmcnt(0) + raw s_barrier (buf reuse safe).
// LDS layout: A0[16K] A1[16K] B0[24K] B1[24K] = 80 KiB (2 blocks/CU).

#define ISSUE(NB) do {                                                        \
    _Pragma("unroll")                                                         \
    for (int j = 0; j < 4; ++j)                                               \
        async_copy16(gptr[j], smem + loff[j] + (NB) * 16384);                 \
    _Pragma("unroll")                                                         \
    for (int j = 4; j < 10; ++j)                                              \
        async_copy16(gptr[j], smem + loff[j] + (NB) * 24576);                 \
    _Pragma("unroll")                                                         \
    for (int j = 0; j < 10; ++j) gptr[j] += 64;                               \
} while (0)

#define COMPUTE(CB) do {                                                      \
    const char* Ab = smem + (CB) * 16384;                                     \
    const char* Bb = smem + 32768 + (CB) * 24576;                             \
    _Pragma("unroll")                                                         \
    for (int ks = 0; ks < 2; ++ks) {                                          \
        const int px = pc ^ (ks << 6);                                        \
        bf16x8 af[4];                                                         \
        _Pragma("unroll")                                                     \
        for (int mt = 0; mt < 4; ++mt)                                        \
            af[mt] = *reinterpret_cast<const bf16x8*>(Ab + arow + mt * 2048 + px); \
        bf16x8 bfr[3][2];                                                     \
        _Pragma("unroll")                                                     \
        for (int g = 0; g < 3; ++g)                                           \
            _Pragma("unroll")                                                 \
            for (int nt = 0; nt < 2; ++nt)                                    \
                bfr[g][nt] = *reinterpret_cast<const bf16x8*>(                \
                    Bb + g * 8192 + brow + nt * 2048 + px);                   \
        _Pragma("unroll")                                                     \
        for (int g = 0; g < 3; ++g)                                           \
            _Pragma("unroll")                                                 \
            for (int mt = 0; mt < 4; ++mt)                                    \
                _Pragma("unroll")                                             \
                for (int nt = 0; nt < 2; ++nt)                                \
                    acc[g][mt][nt] = __builtin_amdgcn_mfma_f32_16x16x32_bf16( \
                        af[mt], bfr[g][nt], acc[g][mt][nt], 0, 0, 0);         \
    }                                                                         \
} while (0)

#define STEP(CB, NB, LAST) do {                                               \
    if (!(LAST)) {                                                            \
        ISSUE(NB);                                                            \
        asm volatile("s_waitcnt vmcnt(10)" ::: "memory");                     \
    } else {                                                                  \
        asm volatile("s_waitcnt vmcnt(0)" ::: "memory");                      \
    }                                                                         \
    __builtin_amdgcn_s_barrier();                                             \
    COMPUTE(CB);                                                              \
    asm volatile("s_waitcnt lgkmcnt(0)" ::: "memory");                        \
    __builtin_amdgcn_s_barrier();                                             \
} while (0)

__global__ __launch_bounds__(256, 2) void gemm_gates(
    const unsigned short* __restrict__ xb,
    const unsigned short* __restrict__ Wb,
    const float* __restrict__ bf_p, const float* __restrict__ bi_p,
    const float* __restrict__ bh_p,
    unsigned short* __restrict__ F, unsigned short* __restrict__ V) {
    __shared__ char smem[81920];

    const int tid  = threadIdx.x;
    const int wave = tid >> 6;
    const int lane = tid & 63;
    const int bh   = blockIdx.x;        // h-tile  [0,16)
    const int bm   = blockIdx.y;        // m-tile  [0,128)
    const int wm   = wave >> 1;
    const int wh   = wave & 1;

    // staging: lane writes LDS row lr, chunk (lane&7); fetches global chunk
    // (lane&7)^lr  (XOR swizzle)
    const int lr = lane >> 3;
    const int gc = (((lane & 7) ^ lr) << 3);

    const unsigned short* gptr[10];
    int loff[10];
#pragma unroll
    for (int j = 0; j < 10; ++j) {
        int s = wave + j * 4;
        if (s < 16) {                   // A segments (j<4 for all waves)
            int row = bm * 128 + s * 8 + lr;
            gptr[j] = xb + (size_t)row * DD + gc;
            loff[j] = s * 1024;
        } else {                        // B segments
            int u = s - 16;             // 0..23
            int row = (u >> 3) * HH + bh * 64 + (u & 7) * 8 + lr;
            gptr[j] = Wb + (size_t)row * DD + gc;
            loff[j] = 32768 + u * 1024;
        }
    }

    // compute-side lane constants (byte offsets)
    const int pc   = (((lane >> 4) ^ (lane & 7)) << 4);
    const int arow = (wm * 64 + (lane & 15)) * 128;
    const int brow = (wh * 32 + (lane & 15)) * 128;

    f32x4 acc[3][4][2];
#pragma unroll
    for (int g = 0; g < 3; ++g)
#pragma unroll
        for (int mt = 0; mt < 4; ++mt)
#pragma unroll
            for (int nt = 0; nt < 2; ++nt)
                acc[g][mt][nt] = (f32x4){0.f, 0.f, 0.f, 0.f};

    ISSUE(0);                           // prologue: tile 0 -> buf 0
    for (int t = 0; t < 7; ++t) {       // kb = 0..13
        STEP(0, 1, 0);
        STEP(1, 0, 0);
    }
    STEP(0, 1, 0);                      // kb = 14, prefetch tile15 -> buf1
    STEP(1, 0, 1);                      // kb = 15, last

    // epilogue: bias + normalized gates, write f and v (bf16)
    const int m0  = bm * 128 + wm * 64 + (lane >> 4) * 4;
    const int h0i = bh * 64 + wh * 32 + (lane & 15);
#pragma unroll
    for (int nt = 0; nt < 2; ++nt) {
        const int h = h0i + nt * 16;
        const float bfs = bf_p[h], bis = bi_p[h], bhs = bh_p[h];
#pragma unroll
        for (int mt = 0; mt < 4; ++mt) {
#pragma unroll
            for (int r = 0; r < 4; ++r) {
                const int m = m0 + mt * 16 + r;
                float zf = acc[0][mt][nt][r] + bfs;
                float zi = acc[1][mt][nt][r] + bis;
                float zh = acc[2][mt][nt][r] + bhs;
                float d  = softplusf(-zf) - softplusf(-zi);
                float f  = 1.0f / (1.0f + __expf(d));   // sigmoid(-d)
                float iv = 1.0f - f;                    // sigmoid(d)
                float gg = g_fn(zh);
                size_t o = (size_t)m * HH + h;
                F[o] = f2bf(f);
                V[o] = f2bf(iv * gg);
            }
        }
    }
}

// ---------------- scan (3-pass chunked linear scan) ----------------
// h_t = f_t*h_{t-1} + v_t ; f+i=1 convex combination -> stable in fp32.
// F/V in bf16, summaries and output fp32.

__global__ void scan1_kernel(const unsigned short* __restrict__ F,
                             const unsigned short* __restrict__ V,
                             float* __restrict__ Fc, float* __restrict__ Vc) {
    const int bx = blockIdx.x, tid = threadIdx.x;
    const int c = bx & (NC - 1), b = bx >> 7;
    const ushort4* F4 = (const ushort4*)F;
    const ushort4* V4 = (const ushort4*)V;
    size_t base = ((size_t)(b * TT + c * CL) * HH) / 4 + tid;
    float4 Fp = {1.f, 1.f, 1.f, 1.f}, hv = {0.f, 0.f, 0.f, 0.f};
#pragma unroll 8
    for (int s = 0; s < CL; ++s) {
        ushort4 fu = F4[base + (size_t)s * (HH / 4)];
        ushort4 vu = V4[base + (size_t)s * (HH / 4)];
        hv.x = fmaf(bf2f(fu.x), hv.x, bf2f(vu.x)); Fp.x *= bf2f(fu.x);
        hv.y = fmaf(bf2f(fu.y), hv.y, bf2f(vu.y)); Fp.y *= bf2f(fu.y);
        hv.z = fmaf(bf2f(fu.z), hv.z, bf2f(vu.z)); Fp.z *= bf2f(fu.z);
        hv.w = fmaf(bf2f(fu.w), hv.w, bf2f(vu.w)); Fp.w *= bf2f(fu.w);
    }
    size_t ci = ((size_t)(b * NC + c) * HH) / 4 + tid;
    ((float4*)Fc)[ci] = Fp;
    ((float4*)Vc)[ci] = hv;
}

__global__ void scan2_kernel(const float* __restrict__ h0,
                             const float* __restrict__ Fc,
                             const float* __restrict__ Vc,
                             float* __restrict__ Hin) {
    const int gid = blockIdx.x * 256 + threadIdx.x;   // 0..4095
    const int b = gid >> 10, h = gid & (HH - 1);
    float carry = g_fn(h0[gid]);
#pragma unroll 8
    for (int c = 0; c < NC; ++c) {
        int ci = (b * NC + c) * HH + h;
        Hin[ci] = carry;
        carry = fmaf(Fc[ci], carry, Vc[ci]);
    }
}

__global__ void scan3_kernel(const unsigned short* __restrict__ F,
                             const unsigned short* __restrict__ V,
                             const float* __restrict__ Hin,
                             float* __restrict__ Out) {
    const int bx = blockIdx.x, tid = threadIdx.x;
    const int c = bx & (NC - 1), b = bx >> 7;
    const ushort4* F4 = (const ushort4*)F;
    const ushort4* V4 = (const ushort4*)V;
    float4* O4 = (float4*)Out;
    size_t base = ((size_t)(b * TT + c * CL) * HH) / 4 + tid;
    size_t ci = ((size_t)(b * NC + c) * HH) / 4 + tid;
    float4 carry = ((const float4*)Hin)[ci];
#pragma unroll 8
    for (int s = 0; s < CL; ++s) {
        size_t idx = base + (size_t)s * (HH / 4);
        ushort4 fu = F4[idx];
        ushort4 vu = V4[idx];
        carry.x = fmaf(bf2f(fu.x), carry.x, bf2f(vu.x));
        carry.y = fmaf(bf2f(fu.y), carry.y, bf2f(vu.y));
        carry.z = fmaf(bf2f(fu.z), carry.z, bf2f(vu.z));
        carry.w = fmaf(bf2f(fu.w), carry.w, bf2f(vu.w));
        O4[idx] = carry;
    }
}

// ---------------- launch ----------------

extern "C" void kernel_launch(void* const* d_in, const int* in_sizes, int n_in,
                              void* d_out, int out_size, void* d_ws, size_t ws_size,
                              hipStream_t stream) {
    const float* x   = (const float*)d_in[0];
    const float* h0  = (const float*)d_in[1];
    const float* Wf  = (const float*)d_in[2];
    const float* bfp = (const float*)d_in[3];
    const float* Wi  = (const float*)d_in[4];
    const float* bip = (const float*)d_in[5];
    const float* Wh  = (const float*)d_in[6];
    const float* bhp = (const float*)d_in[7];
    float* out = (float*)d_out;

    char* ws = (char*)d_ws;
    unsigned short* xb = (unsigned short*)ws;                   // 32 MiB bf16 x
    unsigned short* Wb = (unsigned short*)(ws + 33554432);      // 6 MiB bf16 W
    unsigned short* Fb = (unsigned short*)(ws + 39845888);      // 32 MiB bf16 f
    unsigned short* Vb = (unsigned short*)(ws + 73400320);      // 32 MiB bf16 v
    float* Fc  = (float*)(ws);                                  // 2 MiB (aliases xb)
    float* Vc  = (float*)(ws + 2097152);                        // 2 MiB
    float* Hin = (float*)(ws + 4194304);                        // 2 MiB

    cast_all<<<19456, 256, 0, stream>>>(x, Wf, Wi, Wh, xb, Wb);
    gemm_gates<<<dim3(HH / 64, MM / 128), 256, 0, stream>>>(xb, Wb, bfp, bip, bhp,
                                                            Fb, Vb);
    scan1_kernel<<<BB * NC, 256, 0, stream>>>(Fb, Vb, Fc, Vc);
    scan2_kernel<<<16, 256, 0, stream>>>(h0, Fc, Vc, Hin);
    scan3_kernel<<<BB * NC, 256, 0, stream>>>(Fb, Vb, Hin, out);
}

// Round 4
// 365.968 us; speedup vs baseline: 1.0963x; 1.0271x over previous
//
#include <hip/hip_runtime.h>
#include <stdint.h>

// Problem constants (fixed shapes)
#define BB 4
#define TT 4096
#define DD 1024
#define HH 1024
#define MM (BB * TT)      // 16384
#define NC 128            // scan chunks
#define CL (TT / NC)      // 32 steps per chunk

typedef __bf16 bf16x8 __attribute__((ext_vector_type(8)));
typedef float f32x4 __attribute__((ext_vector_type(4)));

// ---------------- helpers ----------------

__device__ __forceinline__ unsigned short f2bf(float f) {
    unsigned u = __float_as_uint(f);
    u += 0x7fffu + ((u >> 16) & 1u);   // round-to-nearest-even
    return (unsigned short)(u >> 16);
}

__device__ __forceinline__ float bf2f(unsigned short u) {
    return __uint_as_float(((unsigned)u) << 16);
}

__device__ __forceinline__ float softplusf(float x) {
    return (x > 15.f) ? x : log1pf(__expf(x));
}

__device__ __forceinline__ float g_fn(float x) {
    return (x >= 0.f) ? (x + 0.5f) : 1.0f / (1.0f + __expf(-x));
}

// async global->LDS, 16B per lane; hardware dest = wave-uniform base + lane*16
__device__ __forceinline__ void async_copy16(const void* gsrc, void* ldst) {
    __builtin_amdgcn_global_load_lds(
        reinterpret_cast<__attribute__((address_space(1))) unsigned int*>(
            reinterpret_cast<uintptr_t>(gsrc)),
        reinterpret_cast<__attribute__((address_space(3))) unsigned int*>(
            reinterpret_cast<uintptr_t>(ldst)),
        16, 0, 0);
}

// ---------------- fused cast kernel ----------------

__global__ void cast_all(const float* __restrict__ x,
                         const float* __restrict__ Wf,
                         const float* __restrict__ Wi,
                         const float* __restrict__ Wh,
                         unsigned short* __restrict__ xb,
                         unsigned short* __restrict__ Wb) {
    const int NX = MM * DD / 4;                 // 4194304 float4s of x
    int i = blockIdx.x * 256 + threadIdx.x;
    if (i < NX) {
        float4 v = reinterpret_cast<const float4*>(x)[i];
        ushort4 o;
        o.x = f2bf(v.x); o.y = f2bf(v.y); o.z = f2bf(v.z); o.w = f2bf(v.w);
        reinterpret_cast<ushort4*>(xb)[i] = o;
    } else {
        int j = i - NX;                         // 0 .. 786431
        if (j < 3 * 262144) {
            int which = j >> 18, k = j & 262143;
            const float* s = (which == 0) ? Wf : ((which == 1) ? Wi : Wh);
            float4 v = reinterpret_cast<const float4*>(s)[k];
            ushort4 o;
            o.x = f2bf(v.x); o.y = f2bf(v.y); o.z = f2bf(v.z); o.w = f2bf(v.w);
            reinterpret_cast<ushort4*>(Wb)[(which << 18) + k] = o;
        }
    }
}

// ---------------- fused 3-gate GEMM + gate math ----------------
// Block tile: 128(m) x 64(h), 3 gates; 512 threads = 8 waves in a 4x2 grid,
// each wave owns a 32x32 patch for ALL 3 gates: 2x2x3 = 12 16x16 tiles ->
// 48 acc regs/lane (occupancy lever: ~105 unified regs -> 4 waves/SIMD,
// 16 waves/CU, vs R2/R3's 8). Single-buffered 40 KiB LDS, XOR swizzle
// (conflict-free, verified R2), plain __syncthreads (dbuf regressed, R3).

__global__ __launch_bounds__(512, 4) void gemm_gates(
    const unsigned short* __restrict__ xb,
    const unsigned short* __restrict__ Wb,
    const float* __restrict__ bf_p, const float* __restrict__ bi_p,
    const float* __restrict__ bh_p,
    unsigned short* __restrict__ F, unsigned short* __restrict__ V) {
    __shared__ char smem[40960];        // A[16 KiB] | B[24 KiB]

    const int tid  = threadIdx.x;
    const int wave = tid >> 6;          // 0..7
    const int lane = tid & 63;
    const int bh   = blockIdx.x;        // h-tile  [0,16)
    const int bm   = blockIdx.y;        // m-tile  [0,128)
    const int pm   = wave >> 1;         // 0..3  (32-row m patch)
    const int ph   = wave & 1;          // 0..1  (32-col h patch)

    // staging: lane writes LDS row lr, chunk (lane&7); fetches global chunk
    // (lane&7)^lr  (XOR swizzle).  40 segments over 8 waves = 5 per wave:
    // j=0,1 -> A seg s=wave+8j ; j=2,3,4 -> B gate j-2, seg row wave.
    const int lr = lane >> 3;
    const int gc = (((lane & 7) ^ lr) << 3);

    const unsigned short* gptr[5];
    int loff[5];
#pragma unroll
    for (int j = 0; j < 2; ++j) {
        int s = wave + j * 8;           // 0..15
        int row = bm * 128 + s * 8 + lr;
        gptr[j] = xb + (size_t)row * DD + gc;
        loff[j] = s * 1024;
    }
#pragma unroll
    for (int j = 2; j < 5; ++j) {
        int u = wave + (j - 2) * 8;     // 0..23 : gate = j-2, row-seg = wave
        int row = (j - 2) * HH + bh * 64 + wave * 8 + lr;
        gptr[j] = Wb + (size_t)row * DD + gc;
        loff[j] = 16384 + u * 1024;
    }

    // compute-side lane constants (byte offsets)
    const int pc   = (((lane >> 4) ^ (lane & 7)) << 4);
    const int arow = (pm * 32 + (lane & 15)) * 128;
    const int brow = (ph * 32 + (lane & 15)) * 128;

    f32x4 acc[3][2][2];
#pragma unroll
    for (int g = 0; g < 3; ++g)
#pragma unroll
        for (int mt = 0; mt < 2; ++mt)
#pragma unroll
            for (int nt = 0; nt < 2; ++nt)
                acc[g][mt][nt] = (f32x4){0.f, 0.f, 0.f, 0.f};

    for (int kb = 0; kb < 16; ++kb) {
#pragma unroll
        for (int j = 0; j < 5; ++j) async_copy16(gptr[j], smem + loff[j]);
        __syncthreads();   // drains vmcnt -> LDS valid

#pragma unroll
        for (int ks = 0; ks < 2; ++ks) {
            const int px = pc ^ (ks << 6);
            bf16x8 af[2];
#pragma unroll
            for (int mt = 0; mt < 2; ++mt)
                af[mt] = *reinterpret_cast<const bf16x8*>(
                    smem + arow + mt * 2048 + px);
            bf16x8 bfr[3][2];
#pragma unroll
            for (int g = 0; g < 3; ++g)
#pragma unroll
                for (int nt = 0; nt < 2; ++nt)
                    bfr[g][nt] = *reinterpret_cast<const bf16x8*>(
                        smem + 16384 + g * 8192 + brow + nt * 2048 + px);
#pragma unroll
            for (int g = 0; g < 3; ++g)
#pragma unroll
                for (int mt = 0; mt < 2; ++mt)
#pragma unroll
                    for (int nt = 0; nt < 2; ++nt)
                        acc[g][mt][nt] = __builtin_amdgcn_mfma_f32_16x16x32_bf16(
                            af[mt], bfr[g][nt], acc[g][mt][nt], 0, 0, 0);
        }
        __syncthreads();   // all waves done reading before restage
#pragma unroll
        for (int j = 0; j < 5; ++j) gptr[j] += 64;   // next 64-elem K slab
    }

    // epilogue: bias + normalized gates, write f and v (bf16)
    const int m0  = bm * 128 + pm * 32 + (lane >> 4) * 4;
    const int h0i = bh * 64 + ph * 32 + (lane & 15);
#pragma unroll
    for (int nt = 0; nt < 2; ++nt) {
        const int h = h0i + nt * 16;
        const float bfs = bf_p[h], bis = bi_p[h], bhs = bh_p[h];
#pragma unroll
        for (int mt = 0; mt < 2; ++mt) {
#pragma unroll
            for (int r = 0; r < 4; ++r) {
                const int m = m0 + mt * 16 + r;
                float zf = acc[0][mt][nt][r] + bfs;
                float zi = acc[1][mt][nt][r] + bis;
                float zh = acc[2][mt][nt][r] + bhs;
                float d  = softplusf(-zf) - softplusf(-zi);
                float f  = 1.0f / (1.0f + __expf(d));   // sigmoid(-d)
                float iv = 1.0f - f;                    // sigmoid(d)
                float gg = g_fn(zh);
                size_t o = (size_t)m * HH + h;
                F[o] = f2bf(f);
                V[o] = f2bf(iv * gg);
            }
        }
    }
}

// ---------------- scan (3-pass chunked linear scan) ----------------
// h_t = f_t*h_{t-1} + v_t ; f+i=1 convex combination -> stable in fp32.
// F/V in bf16, summaries and output fp32.

__global__ void scan1_kernel(const unsigned short* __restrict__ F,
                             const unsigned short* __restrict__ V,
                             float* __restrict__ Fc, float* __restrict__ Vc) {
    const int bx = blockIdx.x, tid = threadIdx.x;
    const int c = bx & (NC - 1), b = bx >> 7;
    const ushort4* F4 = (const ushort4*)F;
    const ushort4* V4 = (const ushort4*)V;
    size_t base = ((size_t)(b * TT + c * CL) * HH) / 4 + tid;
    float4 Fp = {1.f, 1.f, 1.f, 1.f}, hv = {0.f, 0.f, 0.f, 0.f};
#pragma unroll 8
    for (int s = 0; s < CL; ++s) {
        ushort4 fu = F4[base + (size_t)s * (HH / 4)];
        ushort4 vu = V4[base + (size_t)s * (HH / 4)];
        hv.x = fmaf(bf2f(fu.x), hv.x, bf2f(vu.x)); Fp.x *= bf2f(fu.x);
        hv.y = fmaf(bf2f(fu.y), hv.y, bf2f(vu.y)); Fp.y *= bf2f(fu.y);
        hv.z = fmaf(bf2f(fu.z), hv.z, bf2f(vu.z)); Fp.z *= bf2f(fu.z);
        hv.w = fmaf(bf2f(fu.w), hv.w, bf2f(vu.w)); Fp.w *= bf2f(fu.w);
    }
    size_t ci = ((size_t)(b * NC + c) * HH) / 4 + tid;
    ((float4*)Fc)[ci] = Fp;
    ((float4*)Vc)[ci] = hv;
}

__global__ void scan2_kernel(const float* __restrict__ h0,
                             const float* __restrict__ Fc,
                             const float* __restrict__ Vc,
                             float* __restrict__ Hin) {
    const int gid = blockIdx.x * 256 + threadIdx.x;   // 0..4095
    const int b = gid >> 10, h = gid & (HH - 1);
    float carry = g_fn(h0[gid]);
#pragma unroll 8
    for (int c = 0; c < NC; ++c) {
        int ci = (b * NC + c) * HH + h;
        Hin[ci] = carry;
        carry = fmaf(Fc[ci], carry, Vc[ci]);
    }
}

__global__ void scan3_kernel(const unsigned short* __restrict__ F,
                             const unsigned short* __restrict__ V,
                             const float* __restrict__ Hin,
                             float* __restrict__ Out) {
    const int bx = blockIdx.x, tid = threadIdx.x;
    const int c = bx & (NC - 1), b = bx >> 7;
    const ushort4* F4 = (const ushort4*)F;
    const ushort4* V4 = (const ushort4*)V;
    float4* O4 = (float4*)Out;
    size_t base = ((size_t)(b * TT + c * CL) * HH) / 4 + tid;
    size_t ci = ((size_t)(b * NC + c) * HH) / 4 + tid;
    float4 carry = ((const float4*)Hin)[ci];
#pragma unroll 8
    for (int s = 0; s < CL; ++s) {
        size_t idx = base + (size_t)s * (HH / 4);
        ushort4 fu = F4[idx];
        ushort4 vu = V4[idx];
        carry.x = fmaf(bf2f(fu.x), carry.x, bf2f(vu.x));
        carry.y = fmaf(bf2f(fu.y), carry.y, bf2f(vu.y));
        carry.z = fmaf(bf2f(fu.z), carry.z, bf2f(vu.z));
        carry.w = fmaf(bf2f(fu.w), carry.w, bf2f(vu.w));
        O4[idx] = carry;
    }
}

// ---------------- launch ----------------

extern "C" void kernel_launch(void* const* d_in, const int* in_sizes, int n_in,
                              void* d_out, int out_size, void* d_ws, size_t ws_size,
                              hipStream_t stream) {
    const float* x   = (const float*)d_in[0];
    const float* h0  = (const float*)d_in[1];
    const float* Wf  = (const float*)d_in[2];
    const float* bfp = (const float*)d_in[3];
    const float* Wi  = (const float*)d_in[4];
    const float* bip = (const float*)d_in[5];
    const float* Wh  = (const float*)d_in[6];
    const float* bhp = (const float*)d_in[7];
    float* out = (float*)d_out;

    char* ws = (char*)d_ws;
    unsigned short* xb = (unsigned short*)ws;                   // 32 MiB bf16 x
    unsigned short* Wb = (unsigned short*)(ws + 33554432);      // 6 MiB bf16 W
    unsigned short* Fb = (unsigned short*)(ws + 39845888);      // 32 MiB bf16 f
    unsigned short* Vb = (unsigned short*)(ws + 73400320);      // 32 MiB bf16 v
    float* Fc  = (float*)(ws);                                  // 2 MiB (aliases xb)
    float* Vc  = (float*)(ws + 2097152);                        // 2 MiB
    float* Hin = (float*)(ws + 4194304);                        // 2 MiB

    cast_all<<<19456, 256, 0, stream>>>(x, Wf, Wi, Wh, xb, Wb);
    gemm_gates<<<dim3(HH / 64, MM / 128), 512, 0, stream>>>(xb, Wb, bfp, bip, bhp,
                                                            Fb, Vb);
    scan1_kernel<<<BB * NC, 256, 0, stream>>>(Fb, Vb, Fc, Vc);
    scan2_kernel<<<16, 256, 0, stream>>>(h0, Fc, Vc, Hin);
    scan3_kernel<<<BB * NC, 256, 0, stream>>>(Fb, Vb, Hin, out);
}

// Round 5
// 359.965 us; speedup vs baseline: 1.1146x; 1.0167x over previous
//
#include <hip/hip_runtime.h>
#include <stdint.h>

// Problem constants (fixed shapes)
#define BB 4
#define TT 4096
#define DD 1024
#define HH 1024
#define MM (BB * TT)      // 16384
#define NC 128            // scan chunks
#define CL (TT / NC)      // 32 steps per chunk

typedef __bf16 bf16x8 __attribute__((ext_vector_type(8)));
typedef float f32x4 __attribute__((ext_vector_type(4)));

// ---------------- helpers ----------------

__device__ __forceinline__ unsigned short f2bf(float f) {
    unsigned u = __float_as_uint(f);
    u += 0x7fffu + ((u >> 16) & 1u);   // round-to-nearest-even
    return (unsigned short)(u >> 16);
}

__device__ __forceinline__ float bf2f(unsigned short u) {
    return __uint_as_float(((unsigned)u) << 16);
}

__device__ __forceinline__ float softplusf(float x) {
    return (x > 15.f) ? x : log1pf(__expf(x));
}

__device__ __forceinline__ float g_fn(float x) {
    return (x >= 0.f) ? (x + 0.5f) : 1.0f / (1.0f + __expf(-x));
}

// async global->LDS, 16B per lane; hardware dest = wave-uniform base + lane*16
__device__ __forceinline__ void async_copy16(const void* gsrc, void* ldst) {
    __builtin_amdgcn_global_load_lds(
        reinterpret_cast<__attribute__((address_space(1))) unsigned int*>(
            reinterpret_cast<uintptr_t>(gsrc)),
        reinterpret_cast<__attribute__((address_space(3))) unsigned int*>(
            reinterpret_cast<uintptr_t>(ldst)),
        16, 0, 0);
}

// ---------------- fused cast kernel ----------------

__global__ void cast_all(const float* __restrict__ x,
                         const float* __restrict__ Wf,
                         const float* __restrict__ Wi,
                         const float* __restrict__ Wh,
                         unsigned short* __restrict__ xb,
                         unsigned short* __restrict__ Wb) {
    const int NX = MM * DD / 4;                 // 4194304 float4s of x
    int i = blockIdx.x * 256 + threadIdx.x;
    if (i < NX) {
        float4 v = reinterpret_cast<const float4*>(x)[i];
        ushort4 o;
        o.x = f2bf(v.x); o.y = f2bf(v.y); o.z = f2bf(v.z); o.w = f2bf(v.w);
        reinterpret_cast<ushort4*>(xb)[i] = o;
    } else {
        int j = i - NX;                         // 0 .. 786431
        if (j < 3 * 262144) {
            int which = j >> 18, k = j & 262143;
            const float* s = (which == 0) ? Wf : ((which == 1) ? Wi : Wh);
            float4 v = reinterpret_cast<const float4*>(s)[k];
            ushort4 o;
            o.x = f2bf(v.x); o.y = f2bf(v.y); o.z = f2bf(v.z); o.w = f2bf(v.w);
            reinterpret_cast<ushort4*>(Wb)[(which << 18) + k] = o;
        }
    }
}

// ---------------- fused 3-gate GEMM + gate math ----------------
// Block tile: 128(m) x 64(h), 3 gates; 512 threads = 8 waves in 4x2, each
// wave a 32x32 patch x 3 gates -> 48 acc regs/lane (R4 config: 16 waves/CU).
// NEW vs R4:
//  (a) double-buffered LDS (80 KiB, still 2 blocks/CU) with AITER-style
//      s_waitcnt vmcnt(5) + RAW s_barrier (no compiler vmcnt(0) drain):
//      next tile's 5 loads stay in flight across the barrier.
//  (b) XCD swizzle: concurrent blocks on one XCD share bh -> B L2-resident.

#define ISSUE(NB) do {                                                        \
    _Pragma("unroll")                                                         \
    for (int j = 0; j < 2; ++j)                                               \
        async_copy16(gptrA[j], smem + loffA[j] + (NB) * 16384);               \
    _Pragma("unroll")                                                         \
    for (int j = 0; j < 3; ++j)                                               \
        async_copy16(gptrB[j], smem + 32768 + loffB[j] + (NB) * 24576);       \
    _Pragma("unroll")                                                         \
    for (int j = 0; j < 2; ++j) gptrA[j] += 64;                               \
    _Pragma("unroll")                                                         \
    for (int j = 0; j < 3; ++j) gptrB[j] += 64;                               \
} while (0)

#define COMPUTE(CB) do {                                                      \
    const char* Ab = smem + (CB) * 16384;                                     \
    const char* Bb = smem + 32768 + (CB) * 24576;                             \
    _Pragma("unroll")                                                         \
    for (int ks = 0; ks < 2; ++ks) {                                          \
        const int px = pc ^ (ks << 6);                                        \
        bf16x8 af[2];                                                         \
        _Pragma("unroll")                                                     \
        for (int mt = 0; mt < 2; ++mt)                                        \
            af[mt] = *reinterpret_cast<const bf16x8*>(Ab + arow + mt * 2048 + px); \
        bf16x8 bfr[3][2];                                                     \
        _Pragma("unroll")                                                     \
        for (int g = 0; g < 3; ++g)                                           \
            _Pragma("unroll")                                                 \
            for (int nt = 0; nt < 2; ++nt)                                    \
                bfr[g][nt] = *reinterpret_cast<const bf16x8*>(                \
                    Bb + g * 8192 + brow + nt * 2048 + px);                   \
        _Pragma("unroll")                                                     \
        for (int g = 0; g < 3; ++g)                                           \
            _Pragma("unroll")                                                 \
            for (int mt = 0; mt < 2; ++mt)                                    \
                _Pragma("unroll")                                             \
                for (int nt = 0; nt < 2; ++nt)                                \
                    acc[g][mt][nt] = __builtin_amdgcn_mfma_f32_16x16x32_bf16( \
                        af[mt], bfr[g][nt], acc[g][mt][nt], 0, 0, 0);         \
    }                                                                         \
} while (0)

#define STEP(CB, NB, LAST) do {                                               \
    if (!(LAST)) {                                                            \
        ISSUE(NB);                                                            \
        asm volatile("s_waitcnt vmcnt(5)" ::: "memory");                      \
    } else {                                                                  \
        asm volatile("s_waitcnt vmcnt(0)" ::: "memory");                      \
    }                                                                         \
    __builtin_amdgcn_s_barrier();                                             \
    COMPUTE(CB);                                                              \
    asm volatile("s_waitcnt lgkmcnt(0)" ::: "memory");                        \
    __builtin_amdgcn_s_barrier();                                             \
} while (0)

__global__ __launch_bounds__(512, 4) void gemm_gates(
    const unsigned short* __restrict__ xb,
    const unsigned short* __restrict__ Wb,
    const float* __restrict__ bf_p, const float* __restrict__ bi_p,
    const float* __restrict__ bh_p,
    unsigned short* __restrict__ F, unsigned short* __restrict__ V) {
    __shared__ char smem[81920];        // A0|A1 (32 KiB) + B0|B1 (48 KiB)

    const int tid  = threadIdx.x;
    const int wave = tid >> 6;          // 0..7
    const int lane = tid & 63;

    // XCD swizzle: dispatch order i -> XCD i%8. Make concurrent blocks on
    // one XCD share bh so the 384 KB B slice is L2-resident (4 MiB/XCD).
    const int bi  = blockIdx.x;         // 0..2047
    const int xcd = bi & 7;
    const int jj  = bi >> 3;            // 0..255 per-XCD stream
    const int bm  = ((jj & 15) << 3) | xcd;   // [0,128)
    const int bh  = jj >> 4;                  // [0,16)

    const int pm   = wave >> 1;         // 0..3  (32-row m patch)
    const int ph   = wave & 1;          // 0..1  (32-col h patch)

    // staging: lane writes LDS row lr, chunk (lane&7); fetches global chunk
    // (lane&7)^lr  (XOR swizzle, conflict-free verified R2).
    const int lr = lane >> 3;
    const int gc = (((lane & 7) ^ lr) << 3);

    const unsigned short* gptrA[2];
    const unsigned short* gptrB[3];
    int loffA[2], loffB[3];
#pragma unroll
    for (int j = 0; j < 2; ++j) {
        int s = wave + j * 8;           // 0..15
        int row = bm * 128 + s * 8 + lr;
        gptrA[j] = xb + (size_t)row * DD + gc;
        loffA[j] = s * 1024;
    }
#pragma unroll
    for (int j = 0; j < 3; ++j) {       // gate j, row-seg = wave
        int row = j * HH + bh * 64 + wave * 8 + lr;
        gptrB[j] = Wb + (size_t)row * DD + gc;
        loffB[j] = (j * 8 + wave) * 1024;
    }

    // compute-side lane constants (byte offsets)
    const int pc   = (((lane >> 4) ^ (lane & 7)) << 4);
    const int arow = (pm * 32 + (lane & 15)) * 128;
    const int brow = (ph * 32 + (lane & 15)) * 128;

    f32x4 acc[3][2][2];
#pragma unroll
    for (int g = 0; g < 3; ++g)
#pragma unroll
        for (int mt = 0; mt < 2; ++mt)
#pragma unroll
            for (int nt = 0; nt < 2; ++nt)
                acc[g][mt][nt] = (f32x4){0.f, 0.f, 0.f, 0.f};

    ISSUE(0);                           // prologue: tile 0 -> buf 0
    for (int t = 0; t < 7; ++t) {       // kb = 0..13
        STEP(0, 1, 0);
        STEP(1, 0, 0);
    }
    STEP(0, 1, 0);                      // kb = 14, prefetch tile15 -> buf1
    STEP(1, 0, 1);                      // kb = 15, last

    // epilogue: bias + normalized gates, write f and v (bf16)
    const int m0  = bm * 128 + pm * 32 + (lane >> 4) * 4;
    const int h0i = bh * 64 + ph * 32 + (lane & 15);
#pragma unroll
    for (int nt = 0; nt < 2; ++nt) {
        const int h = h0i + nt * 16;
        const float bfs = bf_p[h], bis = bi_p[h], bhs = bh_p[h];
#pragma unroll
        for (int mt = 0; mt < 2; ++mt) {
#pragma unroll
            for (int r = 0; r < 4; ++r) {
                const int m = m0 + mt * 16 + r;
                float zf = acc[0][mt][nt][r] + bfs;
                float zi = acc[1][mt][nt][r] + bis;
                float zh = acc[2][mt][nt][r] + bhs;
                float d  = softplusf(-zf) - softplusf(-zi);
                float f  = 1.0f / (1.0f + __expf(d));   // sigmoid(-d)
                float iv = 1.0f - f;                    // sigmoid(d)
                float gg = g_fn(zh);
                size_t o = (size_t)m * HH + h;
                F[o] = f2bf(f);
                V[o] = f2bf(iv * gg);
            }
        }
    }
}

// ---------------- scan (3-pass chunked linear scan) ----------------
// h_t = f_t*h_{t-1} + v_t ; f+i=1 convex combination -> stable in fp32.
// F/V in bf16, summaries and output fp32.

__global__ void scan1_kernel(const unsigned short* __restrict__ F,
                             const unsigned short* __restrict__ V,
                             float* __restrict__ Fc, float* __restrict__ Vc) {
    const int bx = blockIdx.x, tid = threadIdx.x;
    const int c = bx & (NC - 1), b = bx >> 7;
    const ushort4* F4 = (const ushort4*)F;
    const ushort4* V4 = (const ushort4*)V;
    size_t base = ((size_t)(b * TT + c * CL) * HH) / 4 + tid;
    float4 Fp = {1.f, 1.f, 1.f, 1.f}, hv = {0.f, 0.f, 0.f, 0.f};
#pragma unroll 8
    for (int s = 0; s < CL; ++s) {
        ushort4 fu = F4[base + (size_t)s * (HH / 4)];
        ushort4 vu = V4[base + (size_t)s * (HH / 4)];
        hv.x = fmaf(bf2f(fu.x), hv.x, bf2f(vu.x)); Fp.x *= bf2f(fu.x);
        hv.y = fmaf(bf2f(fu.y), hv.y, bf2f(vu.y)); Fp.y *= bf2f(fu.y);
        hv.z = fmaf(bf2f(fu.z), hv.z, bf2f(vu.z)); Fp.z *= bf2f(fu.z);
        hv.w = fmaf(bf2f(fu.w), hv.w, bf2f(vu.w)); Fp.w *= bf2f(fu.w);
    }
    size_t ci = ((size_t)(b * NC + c) * HH) / 4 + tid;
    ((float4*)Fc)[ci] = Fp;
    ((float4*)Vc)[ci] = hv;
}

__global__ void scan2_kernel(const float* __restrict__ h0,
                             const float* __restrict__ Fc,
                             const float* __restrict__ Vc,
                             float* __restrict__ Hin) {
    const int gid = blockIdx.x * 256 + threadIdx.x;   // 0..4095
    const int b = gid >> 10, h = gid & (HH - 1);
    float carry = g_fn(h0[gid]);
#pragma unroll 8
    for (int c = 0; c < NC; ++c) {
        int ci = (b * NC + c) * HH + h;
        Hin[ci] = carry;
        carry = fmaf(Fc[ci], carry, Vc[ci]);
    }
}

__global__ void scan3_kernel(const unsigned short* __restrict__ F,
                             const unsigned short* __restrict__ V,
                             const float* __restrict__ Hin,
                             float* __restrict__ Out) {
    const int bx = blockIdx.x, tid = threadIdx.x;
    const int c = bx & (NC - 1), b = bx >> 7;
    const ushort4* F4 = (const ushort4*)F;
    const ushort4* V4 = (const ushort4*)V;
    float4* O4 = (float4*)Out;
    size_t base = ((size_t)(b * TT + c * CL) * HH) / 4 + tid;
    size_t ci = ((size_t)(b * NC + c) * HH) / 4 + tid;
    float4 carry = ((const float4*)Hin)[ci];
#pragma unroll 8
    for (int s = 0; s < CL; ++s) {
        size_t idx = base + (size_t)s * (HH / 4);
        ushort4 fu = F4[idx];
        ushort4 vu = V4[idx];
        carry.x = fmaf(bf2f(fu.x), carry.x, bf2f(vu.x));
        carry.y = fmaf(bf2f(fu.y), carry.y, bf2f(vu.y));
        carry.z = fmaf(bf2f(fu.z), carry.z, bf2f(vu.z));
        carry.w = fmaf(bf2f(fu.w), carry.w, bf2f(vu.w));
        O4[idx] = carry;
    }
}

// ---------------- launch ----------------

extern "C" void kernel_launch(void* const* d_in, const int* in_sizes, int n_in,
                              void* d_out, int out_size, void* d_ws, size_t ws_size,
                              hipStream_t stream) {
    const float* x   = (const float*)d_in[0];
    const float* h0  = (const float*)d_in[1];
    const float* Wf  = (const float*)d_in[2];
    const float* bfp = (const float*)d_in[3];
    const float* Wi  = (const float*)d_in[4];
    const float* bip = (const float*)d_in[5];
    const float* Wh  = (const float*)d_in[6];
    const float* bhp = (const float*)d_in[7];
    float* out = (float*)d_out;

    char* ws = (char*)d_ws;
    unsigned short* xb = (unsigned short*)ws;                   // 32 MiB bf16 x
    unsigned short* Wb = (unsigned short*)(ws + 33554432);      // 6 MiB bf16 W
    unsigned short* Fb = (unsigned short*)(ws + 39845888);      // 32 MiB bf16 f
    unsigned short* Vb = (unsigned short*)(ws + 73400320);      // 32 MiB bf16 v
    float* Fc  = (float*)(ws);                                  // 2 MiB (aliases xb)
    float* Vc  = (float*)(ws + 2097152);                        // 2 MiB
    float* Hin = (float*)(ws + 4194304);                        // 2 MiB

    cast_all<<<19456, 256, 0, stream>>>(x, Wf, Wi, Wh, xb, Wb);
    gemm_gates<<<2048, 512, 0, stream>>>(xb, Wb, bfp, bip, bhp, Fb, Vb);
    scan1_kernel<<<BB * NC, 256, 0, stream>>>(Fb, Vb, Fc, Vc);
    scan2_kernel<<<16, 256, 0, stream>>>(h0, Fc, Vc, Hin);
    scan3_kernel<<<BB * NC, 256, 0, stream>>>(Fb, Vb, Hin, out);
}